// Round 1
// baseline (205.041 us; speedup 1.0000x reference)
//
#include <hip/hip_runtime.h>

// DeQuantizer: 4-bit GPTQ-style weight dequantization.
// qweight: int32 [K/8, N], qzeros: int32 [G, N/8], scales: f32 [G, N],
// g_idx: int32 [K] (sorted). out: f32 [K, N].
// out[k][n] = scales[g][n] * (((qw[k/8][n] >> 4*(k%8)) & 15) - ((qz[g][n/8] >> 4*(n%8)) & 15))
// with g = g_idx[k].

#define KK 4096
#define NN 11008
#define GROUPS 32
#define NPACK (NN / 8)   // 1376
#define KPACKS (KK / 8)  // 512
#define N4 (NN / 4)      // 2752

__global__ __launch_bounds__(256) void dequant_kernel(
    const int* __restrict__ qweight,   // [512, N]
    const int* __restrict__ qzeros,    // [32, 1376]
    const float* __restrict__ scales,  // [32, N]
    const int* __restrict__ g_idx,     // [K]
    float* __restrict__ out)           // [K, N]
{
    const int n4 = blockIdx.x * blockDim.x + threadIdx.x;
    const int kp = blockIdx.y;  // k-pack index: rows kp*8 .. kp*8+7
    if (n4 >= N4) return;
    const int n = n4 * 4;

    // 4 consecutive packed-weight words (columns n..n+3 of row kp)
    const int4 qw = *reinterpret_cast<const int4*>(&qweight[kp * NN + n]);

    // group index for each of the 8 rows in this pack (uniform per block -> s_load)
    const int4 g0 = *reinterpret_cast<const int4*>(&g_idx[kp * 8]);
    const int4 g1 = *reinterpret_cast<const int4*>(&g_idx[kp * 8 + 4]);
    const int gs[8] = {g0.x, g0.y, g0.z, g0.w, g1.x, g1.y, g1.z, g1.w};

    // zeros word: columns n..n+3 live in nibbles (n%8)..(n%8+3) of word n/8.
    // n % 8 is 0 or 4, so the base bit shift is 0 or 16.
    const int zsh = (n & 4) * 4;
    const int zword = n >> 3;

    #pragma unroll
    for (int j = 0; j < 8; ++j) {
        const int g = gs[j];
        const int zq = qzeros[g * NPACK + zword] >> zsh;
        const float4 s = *reinterpret_cast<const float4*>(&scales[g * NN + n]);
        const int sh = 4 * j;

        float4 o;
        o.x = s.x * ((float)((qw.x >> sh) & 15) - (float)((zq      ) & 15));
        o.y = s.y * ((float)((qw.y >> sh) & 15) - (float)((zq >>  4) & 15));
        o.z = s.z * ((float)((qw.z >> sh) & 15) - (float)((zq >>  8) & 15));
        o.w = s.w * ((float)((qw.w >> sh) & 15) - (float)((zq >> 12) & 15));

        *reinterpret_cast<float4*>(&out[(size_t)(kp * 8 + j) * NN + n]) = o;
    }
}

extern "C" void kernel_launch(void* const* d_in, const int* in_sizes, int n_in,
                              void* d_out, int out_size, void* d_ws, size_t ws_size,
                              hipStream_t stream) {
    const int*   qweight = (const int*)d_in[0];
    const int*   qzeros  = (const int*)d_in[1];
    const float* scales  = (const float*)d_in[2];
    const int*   g_idx   = (const int*)d_in[3];
    float*       out     = (float*)d_out;

    dim3 block(256);
    dim3 grid((N4 + 255) / 256, KPACKS);  // (11, 512)
    dequant_kernel<<<grid, block, 0, stream>>>(qweight, qzeros, scales, g_idx, out);
}